// Round 16
// baseline (71.479 us; speedup 1.0000x reference)
//
#include <hip/hip_runtime.h>
#include <hip/hip_bf16.h>

#define NB 32768
#define ND 512
#define NS 128
#define NE 8
#define TPE 96  // 64-row tiles per expert (covers cnt up to 6144)

typedef __attribute__((ext_vector_type(8))) short bf16x8;
typedef __attribute__((ext_vector_type(4))) float f32x4;

__device__ __forceinline__ unsigned short f2b(float f) {
  union { __hip_bfloat16 h; unsigned short u; } cv;
  cv.h = __float2bfloat16(f);
  return cv.u;
}

__device__ __forceinline__ bf16x8 relu_cvt8v(float4 a, float4 b) {
  bf16x8 r;
  r[0] = (short)f2b(fmaxf(a.x, 0.f)); r[1] = (short)f2b(fmaxf(a.y, 0.f));
  r[2] = (short)f2b(fmaxf(a.z, 0.f)); r[3] = (short)f2b(fmaxf(a.w, 0.f));
  r[4] = (short)f2b(fmaxf(b.x, 0.f)); r[5] = (short)f2b(fmaxf(b.y, 0.f));
  r[6] = (short)f2b(fmaxf(b.z, 0.f)); r[7] = (short)f2b(fmaxf(b.w, 0.f));
  return r;
}

__device__ __forceinline__ void gload16(const void* gsrc, void* ldst) {
  __builtin_amdgcn_global_load_lds(
      (const __attribute__((address_space(1))) unsigned int*)gsrc,
      (__attribute__((address_space(3))) unsigned int*)ldst, 16, 0, 0);
}

// counted-vmcnt phase barriers (T4); "memory" clobber pins VMEM issue groups.
#define BARV2  asm volatile("s_waitcnt vmcnt(2)\n\ts_barrier" ::: "memory")
#define BARV0  asm volatile("s_waitcnt vmcnt(0)\n\ts_barrier" ::: "memory")
#define BARL   asm volatile("s_waitcnt lgkmcnt(0)\n\ts_barrier" ::: "memory")
#define BARV17 asm volatile("s_waitcnt vmcnt(17)\n\ts_barrier" ::: "memory")
#define BARV2L asm volatile("s_waitcnt vmcnt(2) lgkmcnt(0)\n\ts_barrier" ::: "memory")
#define CFENCE asm volatile("" ::: "memory")

__global__ void zero_counts_k(int* counts) {
  if (threadIdx.x < NE) counts[threadIdx.x] = 0;
}

__global__ void bin_rows_k(const int* __restrict__ yidx, int* __restrict__ counts,
                           int* __restrict__ bucket) {
  __shared__ int lcnt[NE];
  __shared__ int lbase[NE];
  int tid = threadIdx.x;
  if (tid < NE) lcnt[tid] = 0;
  __syncthreads();
  int b = blockIdx.x * blockDim.x + tid;
  int e = yidx[b];
  int pos = atomicAdd(&lcnt[e], 1);
  __syncthreads();
  if (tid < NE) lbase[tid] = atomicAdd(&counts[tid], lcnt[tid]);
  __syncthreads();
  bucket[e * NB + lbase[e] + pos] = b;
}

// [R][C] f32 -> [C][R] bf16, XOR pre-swizzle within 64-short groups so a
// LINEAR global_load_lds copy lands bank-swizzled in LDS.
__global__ void transpose_cvt_k(const float* __restrict__ in,
                                unsigned short* __restrict__ out, int R, int C) {
  __shared__ float lt[32][33];
  int tpm = (R >> 5) * (C >> 5);
  int mat = blockIdx.x / tpm;
  int rem = blockIdx.x % tpm;
  int tcn = C >> 5;
  int tr = rem / tcn, tc = rem % tcn;
  const float* mi = in + (size_t)mat * R * C;
  unsigned short* mo = out + (size_t)mat * R * C;
  int r = threadIdx.x >> 5, c = threadIdx.x & 31;
#pragma unroll
  for (int i = 0; i < 4; ++i) {
    int rr = r + i * 8;
    lt[rr][c] = mi[(size_t)(tr * 32 + rr) * C + tc * 32 + c];
  }
  __syncthreads();
#pragma unroll
  for (int i = 0; i < 4; ++i) {
    int rr = r + i * 8;
    int orow = tc * 32 + rr;
    int d = tr * 32 + c;
    int ocol = (d & ~63) | ((d & 63) ^ ((orow & 7) << 3));
    mo[(size_t)orow * R + ocol] = f2b(lt[c][rr]);
  }
}

// ---- Fused MoE: page-friendly bursts + counted vmcnt ----
#define M1STAGE(c)                                                        \
  do {                                                                    \
    gload16(g0 + (c) * 128, (char*)wt[(c) % 3] + p0 * 16);                \
    gload16(g1 + (c) * 128, (char*)wt[(c) % 3] + p1 * 16);                \
  } while (0)

// stage-1 phase: pure {2 DMA + LDS reads + 8 MFMA}; A-frags from swizzled xt
#define S1_ITER(c)                                                             \
  do {                                                                         \
    if ((c) <= 5) { M1STAGE((c) + 2); }                                        \
    bf16x8 a0 = *(const bf16x8*)((const char*)&xt[arow][0] +                   \
                 ((((c) * 64 + l4 * 8) * 2) ^ arsw));                          \
    bf16x8 a1 = *(const bf16x8*)((const char*)&xt[arow][0] +                   \
                 ((((c) * 64 + 32 + l4 * 8) * 2) ^ arsw));                     \
    const unsigned short* wb = wt[(c) % 3];                                    \
    _Pragma("unroll") for (int nt = 0; nt < 4; ++nt) {                         \
      int n = nh * 64 + nt * 16 + l15;                                         \
      int sw = (n & 7) << 3;                                                   \
      bf16x8 b0 = *(const bf16x8*)&wb[n * 64 + ((l4 * 8) ^ sw)];               \
      bf16x8 b1v = *(const bf16x8*)&wb[n * 64 + ((32 + l4 * 8) ^ sw)];         \
      acc[nt] = __builtin_amdgcn_mfma_f32_16x16x32_bf16(a0, b0, acc[nt], 0, 0, 0);  \
      acc[nt] = __builtin_amdgcn_mfma_f32_16x16x32_bf16(a1, b1v, acc[nt], 0, 0, 0); \
    }                                                                          \
    if ((c) <= 5) { BARV2; } else if ((c) == 6) { BARV0; }                     \
  } while (0)

#define M2STAGE(c)                                                           \
  do {                                                                       \
    gload16(w2e + (c) * 16384 + p0 * 16, (char*)wt[(c) % 3] + p0 * 16);      \
    gload16(w2e + (c) * 16384 + p1 * 16, (char*)wt[(c) % 3] + p1 * 16);      \
  } while (0)

// stage-2 phase: pure {<=2 DMA + 8 MFMA + obuf ds_writes}; barrier per schedule
#define S2_ITER(c)                                                            \
  do {                                                                        \
    if ((c) <= 5) { M2STAGE((c) + 2); }                                       \
    const unsigned short* wb = wt[(c) % 3];                                   \
    f32x4 acc0 = (f32x4){0.f, 0.f, 0.f, 0.f};                                 \
    f32x4 acc1 = (f32x4){0.f, 0.f, 0.f, 0.f};                                 \
    _Pragma("unroll") for (int kk = 0; kk < 4; ++kk) {                        \
      int dl0 = nh * 32 + l15;                                                \
      int sw0 = (dl0 & 7) << 3;                                               \
      bf16x8 bv0 = *(const bf16x8*)&wb[dl0 * 128 + ((kk * 32 + l4 * 8) ^ sw0)]; \
      acc0 = __builtin_amdgcn_mfma_f32_16x16x32_bf16(ha[kk], bv0, acc0, 0, 0, 0); \
      int dl1 = nh * 32 + 16 + l15;                                           \
      int sw1 = (dl1 & 7) << 3;                                               \
      bf16x8 bv1 = *(const bf16x8*)&wb[dl1 * 128 + ((kk * 32 + l4 * 8) ^ sw1)]; \
      acc1 = __builtin_amdgcn_mfma_f32_16x16x32_bf16(ha[kk], bv1, acc1, 0, 0, 0); \
    }                                                                         \
    int cc = (c) & 3;                                                         \
    _Pragma("unroll") for (int r = 0; r < 4; ++r) {                           \
      obuf[rg * 16 + l4 * 4 + r][cc * 64 + nh * 32 + l15] = acc0[r];          \
      obuf[rg * 16 + l4 * 4 + r][cc * 64 + nh * 32 + 16 + l15] = acc1[r];     \
    }                                                                         \
  } while (0)

// write phase: exactly 17 VMEM (1 b2 + 8 x + 8 stores), full-row 1KB bursts.
// Pad rows duplicate row cnt-1 bit-exactly -> unconditional idempotent store.
#define WRITE_PHASE(h)                                                        \
  do {                                                                        \
    float4 b24 = *(const float4*)&b2[e * ND + (h) * 256 + lane * 4];          \
    _Pragma("unroll") for (int j = 0; j < 8; ++j) {                           \
      int row = w * 8 + j;                                                    \
      float4 o4 = *(const float4*)&obuf[row][lane * 4];                       \
      int rid = rowid_s[row];                                                 \
      float zv = zs[row];                                                     \
      float4 x4 = *(const float4*)&x[(size_t)rid * ND + (h) * 256 + lane * 4];\
      float4 res;                                                             \
      res.x = x4.x + (o4.x + b24.x) * zv;                                     \
      res.y = x4.y + (o4.y + b24.y) * zv;                                     \
      res.z = x4.z + (o4.z + b24.z) * zv;                                     \
      res.w = x4.w + (o4.w + b24.w) * zv;                                     \
      *(float4*)&out[(size_t)rid * ND + (h) * 256 + lane * 4] = res;          \
    }                                                                         \
  } while (0)

__launch_bounds__(512, 1)
__global__ void moe_f(const float* __restrict__ x, const float* __restrict__ z,
                      const float* __restrict__ b1, const float* __restrict__ b2,
                      const unsigned short* __restrict__ w1sw,
                      const unsigned short* __restrict__ w2sw,
                      const int* __restrict__ counts, const int* __restrict__ bucket,
                      float* __restrict__ out) {
  __shared__ __align__(16) char xo_raw[64 * 520 * 2];  // xt (s1) / obuf (s2), 66.5 KB
  __shared__ unsigned short wt[3][8192];               // 48 KB weight stream
  __shared__ unsigned short ht[64][136];               // 17 KB H exchange
  __shared__ int rowid_s[64];
  __shared__ float zs[64];
  auto xt = (unsigned short(*)[520])xo_raw;
  auto obuf = (float(*)[260])xo_raw;

  int e = blockIdx.x & 7;  // XCD pin
  int t = blockIdx.x >> 3;
  int cnt = counts[e];
  if (t * 64 >= cnt) return;  // uniform exit before any barrier
  int tid = threadIdx.x, w = tid >> 6, lane = tid & 63;
  int l15 = lane & 15, l4 = lane >> 4;
  int rg = w >> 1, nh = w & 1;

  if (tid < 64) {
    int pos = t * 64 + tid;
    int ps = (pos < cnt) ? pos : (cnt - 1);
    int rid = bucket[e * NB + ps];
    rowid_s[tid] = rid;
    zs[tid] = z[rid];
  }

  // ---- x staging: wave w stages rows w*8..+8, one 2KB burst per row ----
#pragma unroll
  for (int j = 0; j < 8; ++j) {
    int row = w * 8 + j;
    int pos = t * 64 + row;
    int ps = (pos < cnt) ? pos : (cnt - 1);
    int rid = bucket[e * NB + ps];
    const float* xp = x + (size_t)rid * ND + lane * 8;
    float4 a = *(const float4*)xp;
    float4 b = *(const float4*)(xp + 4);
    bf16x8 v = relu_cvt8v(a, b);
    *(bf16x8*)((char*)&xt[row][0] + ((lane * 16) ^ ((row & 7) << 4))) = v;
  }

  const char* w1e = (const char*)w1sw + (size_t)e * NS * ND * 2;
  const char* w2e = (const char*)w2sw + (size_t)e * ND * NS * 2;
  int p0 = tid, p1 = tid + 512;
  const char* g0 = w1e + (p0 >> 3) * 1024 + (p0 & 7) * 16;
  const char* g1 = w1e + (p1 >> 3) * 1024 + (p1 & 7) * 16;

  __syncthreads();  // xt + rowid ready; vmcnt ledger reset

  // ---------------- stage 1 ----------------
  M1STAGE(0);
  CFENCE;
  M1STAGE(1);
  BARV2;  // retire S1(0), keep S1(1) in flight

  f32x4 acc[4];
#pragma unroll
  for (int i = 0; i < 4; ++i) acc[i] = (f32x4){0.f, 0.f, 0.f, 0.f};
  int arow = rg * 16 + l15;
  int arsw = (arow & 7) << 4;

  S1_ITER(0); S1_ITER(1); S1_ITER(2); S1_ITER(3);
  S1_ITER(4); S1_ITER(5); S1_ITER(6); S1_ITER(7);

  // ---------------- transition: H -> ht, W2 prologue ----------------
#pragma unroll
  for (int nt = 0; nt < 4; ++nt) {
    int col = nh * 64 + nt * 16 + l15;
    float bias = b1[e * NS + col];
#pragma unroll
    for (int r = 0; r < 4; ++r)
      ht[rg * 16 + l4 * 4 + r][col] = f2b(fmaxf(acc[nt][r] + bias, 0.f));
  }
  M2STAGE(0);
  CFENCE;
  M2STAGE(1);
  BARV2L;  // retire S2(0); drain ht ds_writes; keep S2(1) in flight

  bf16x8 ha[4];
#pragma unroll
  for (int kk = 0; kk < 4; ++kk)
    ha[kk] = *(const bf16x8*)&ht[rg * 16 + l15][kk * 32 + l4 * 8];

  // ---------------- stage 2: two 256-col halves ----------------
  S2_ITER(0); BARV2;   // retire S2(1)
  S2_ITER(1); BARV2;   // retire S2(2)
  S2_ITER(2); BARV2;   // retire S2(3)
  S2_ITER(3); BARL;    // obuf half-0 visible; S2(4),S2(5) stay in flight
  WRITE_PHASE(0);
  BARV17;              // 17 write-phase ops younger than S2(4),S2(5) -> retire both
  S2_ITER(4); BARV2;   // leaves S2(6)
  S2_ITER(5); BARV2;   // retire S2(6), leaves S2(7)
  S2_ITER(6); BARV0;   // drain S2(7) for last chunk
  S2_ITER(7); BARL;    // obuf half-1 visible
  WRITE_PHASE(1);
}

extern "C" void kernel_launch(void* const* d_in, const int* in_sizes, int n_in,
                              void* d_out, int out_size, void* d_ws, size_t ws_size,
                              hipStream_t stream) {
  const float* x = (const float*)d_in[0];
  const int* yidx = (const int*)d_in[1];
  // d_in[2] = y_hard (unused by reference)
  const float* z = (const float*)d_in[3];
  const float* W1 = (const float*)d_in[4];
  const float* b1 = (const float*)d_in[5];
  const float* W2 = (const float*)d_in[6];
  const float* b2 = (const float*)d_in[7];
  float* out = (float*)d_out;

  char* ws = (char*)d_ws;
  int* counts = (int*)ws;                     // 32 B
  int* bucket = (int*)(ws + 256);             // 1 MB
  size_t off = 256 + (size_t)NE * NB * 4;
  unsigned short* w1sw = (unsigned short*)(ws + off);  // 1 MB (swizzled)
  off += (size_t)NE * NS * ND * 2;
  unsigned short* w2sw = (unsigned short*)(ws + off);  // 1 MB (swizzled)

  zero_counts_k<<<1, 64, 0, stream>>>(counts);
  bin_rows_k<<<NB / 1024, 1024, 0, stream>>>(yidx, counts, bucket);
  // W1 [E][D][S] -> [E][S][D] pre-swizzled; W2 [E][S][D] -> [E][D][S] pre-swizzled
  transpose_cvt_k<<<NE * (ND / 32) * (NS / 32), 256, 0, stream>>>(W1, w1sw, ND, NS);
  transpose_cvt_k<<<NE * (NS / 32) * (ND / 32), 256, 0, stream>>>(W2, w2sw, NS, ND);
  moe_f<<<NE * TPE, 512, 0, stream>>>(x, z, b1, b2, w1sw, w2sw, counts, bucket, out);
}

// Round 17
// 67.633 us; speedup vs baseline: 1.0569x; 1.0569x over previous
//
#include <hip/hip_runtime.h>
#include <hip/hip_bf16.h>

#define NB 32768
#define ND 512
#define NS 128
#define NE 8
#define TPE 96  // 64-row tiles per expert (covers cnt up to 6144)

typedef __attribute__((ext_vector_type(8))) short bf16x8;
typedef __attribute__((ext_vector_type(4))) float f32x4;

__device__ __forceinline__ unsigned short f2b(float f) {
  union { __hip_bfloat16 h; unsigned short u; } cv;
  cv.h = __float2bfloat16(f);
  return cv.u;
}

__device__ __forceinline__ bf16x8 relu_cvt8v(float4 a, float4 b) {
  bf16x8 r;
  r[0] = (short)f2b(fmaxf(a.x, 0.f)); r[1] = (short)f2b(fmaxf(a.y, 0.f));
  r[2] = (short)f2b(fmaxf(a.z, 0.f)); r[3] = (short)f2b(fmaxf(a.w, 0.f));
  r[4] = (short)f2b(fmaxf(b.x, 0.f)); r[5] = (short)f2b(fmaxf(b.y, 0.f));
  r[6] = (short)f2b(fmaxf(b.z, 0.f)); r[7] = (short)f2b(fmaxf(b.w, 0.f));
  return r;
}

__device__ __forceinline__ void gload16(const void* gsrc, void* ldst) {
  __builtin_amdgcn_global_load_lds(
      (const __attribute__((address_space(1))) unsigned int*)gsrc,
      (__attribute__((address_space(3))) unsigned int*)ldst, 16, 0, 0);
}

// counted-vmcnt phase barriers (T4): memory clobber pins VMEM issue order.
#define BARV6  asm volatile("s_waitcnt vmcnt(6)\n\ts_barrier" ::: "memory")
#define BARV12 asm volatile("s_waitcnt vmcnt(12)\n\ts_barrier" ::: "memory")
#define BARV10 asm volatile("s_waitcnt vmcnt(10)\n\ts_barrier" ::: "memory")
#define BARV0  asm volatile("s_waitcnt vmcnt(0)\n\ts_barrier" ::: "memory")
#define BARV2L asm volatile("s_waitcnt vmcnt(2) lgkmcnt(0)\n\ts_barrier" ::: "memory")
#define CFENCE asm volatile("" ::: "memory")

__global__ void zero_counts_k(int* counts) {
  if (threadIdx.x < NE) counts[threadIdx.x] = 0;
}

__global__ void bin_rows_k(const int* __restrict__ yidx, int* __restrict__ counts,
                           int* __restrict__ bucket) {
  __shared__ int lcnt[NE];
  __shared__ int lbase[NE];
  int tid = threadIdx.x;
  if (tid < NE) lcnt[tid] = 0;
  __syncthreads();
  int b = blockIdx.x * blockDim.x + tid;
  int e = yidx[b];
  int pos = atomicAdd(&lcnt[e], 1);
  __syncthreads();
  if (tid < NE) lbase[tid] = atomicAdd(&counts[tid], lcnt[tid]);
  __syncthreads();
  bucket[e * NB + lbase[e] + pos] = b;
}

// [R][C] f32 -> [C][R] bf16, XOR pre-swizzle within 64-short groups so a
// LINEAR global_load_lds copy lands bank-swizzled in LDS.
__global__ void transpose_cvt_k(const float* __restrict__ in,
                                unsigned short* __restrict__ out, int R, int C) {
  __shared__ float lt[32][33];
  int tpm = (R >> 5) * (C >> 5);
  int mat = blockIdx.x / tpm;
  int rem = blockIdx.x % tpm;
  int tcn = C >> 5;
  int tr = rem / tcn, tc = rem % tcn;
  const float* mi = in + (size_t)mat * R * C;
  unsigned short* mo = out + (size_t)mat * R * C;
  int r = threadIdx.x >> 5, c = threadIdx.x & 31;
#pragma unroll
  for (int i = 0; i < 4; ++i) {
    int rr = r + i * 8;
    lt[rr][c] = mi[(size_t)(tr * 32 + rr) * C + tc * 32 + c];
  }
  __syncthreads();
#pragma unroll
  for (int i = 0; i < 4; ++i) {
    int rr = r + i * 8;
    int orow = tc * 32 + rr;
    int d = tr * 32 + c;
    int ocol = (d & ~63) | ((d & 63) ^ ((orow & 7) << 3));
    mo[(size_t)orow * R + ocol] = f2b(lt[c][rr]);
  }
}

// ---- Fused MoE, counted-vmcnt pipeline (R15) + T5 s_setprio on MFMA ----
#define M1LOADX(DST, c)                                 \
  do {                                                  \
    const float* xp = xrow + (c) * 64;                  \
    DST[0] = *(const float4*)(xp);                      \
    DST[1] = *(const float4*)(xp + 4);                  \
    DST[2] = *(const float4*)(xp + 32);                 \
    DST[3] = *(const float4*)(xp + 36);                 \
  } while (0)

#define M1STAGE(c)                                                        \
  do {                                                                    \
    gload16(g0 + (c) * 128, (char*)wt[(c) % 3] + p0 * 16);                \
    gload16(g1 + (c) * 128, (char*)wt[(c) % 3] + p1 * 16);                \
  } while (0)

#define M1_ITER(c, CUR)                                                        \
  do {                                                                         \
    if ((c) <= 5) { M1STAGE((c) + 2); }                                        \
    bf16x8 a0 = relu_cvt8v(CUR[0], CUR[1]);                                    \
    bf16x8 a1 = relu_cvt8v(CUR[2], CUR[3]);                                    \
    if ((c) <= 5) { M1LOADX(CUR, (c) + 2); }                                   \
    const unsigned short* wb = wt[(c) % 3];                                    \
    __builtin_amdgcn_s_setprio(1);                                             \
    _Pragma("unroll") for (int nt = 0; nt < 4; ++nt) {                         \
      int n = nh * 64 + nt * 16 + l15;                                         \
      int sw = (n & 7) << 3;                                                   \
      bf16x8 b0 = *(const bf16x8*)&wb[n * 64 + ((l4 * 8) ^ sw)];               \
      bf16x8 b1v = *(const bf16x8*)&wb[n * 64 + ((32 + l4 * 8) ^ sw)];         \
      acc[nt] = __builtin_amdgcn_mfma_f32_16x16x32_bf16(a0, b0, acc[nt], 0, 0, 0);  \
      acc[nt] = __builtin_amdgcn_mfma_f32_16x16x32_bf16(a1, b1v, acc[nt], 0, 0, 0); \
    }                                                                          \
    __builtin_amdgcn_s_setprio(0);                                             \
    if ((c) <= 5) { BARV6; } else if ((c) == 6) { BARV0; }                     \
  } while (0)

#define M2STAGE(c)                                                           \
  do {                                                                       \
    gload16(w2e + (c) * 16384 + p0 * 16, (char*)wt[(c) % 3] + p0 * 16);      \
    gload16(w2e + (c) * 16384 + p1 * 16, (char*)wt[(c) % 3] + p1 * 16);      \
  } while (0)

#define M2_ITER(c)                                                            \
  do {                                                                        \
    if ((c) <= 5) { M2STAGE((c) + 2); }                                       \
    float xe0[4], xe1[4];                                                     \
    int d0 = (c) * 64 + nh * 32 + l15;                                        \
    int d1 = d0 + 16;                                                         \
    _Pragma("unroll") for (int r = 0; r < 4; ++r) {                           \
      xe0[r] = x[(size_t)orow[r] * ND + d0];                                  \
      xe1[r] = x[(size_t)orow[r] * ND + d1];                                  \
    }                                                                         \
    float bias0 = b2[e * ND + d0];                                            \
    float bias1 = b2[e * ND + d1];                                            \
    const unsigned short* wb = wt[(c) % 3];                                   \
    f32x4 acc0 = (f32x4){0.f, 0.f, 0.f, 0.f};                                 \
    f32x4 acc1 = (f32x4){0.f, 0.f, 0.f, 0.f};                                 \
    __builtin_amdgcn_s_setprio(1);                                            \
    _Pragma("unroll") for (int kk = 0; kk < 4; ++kk) {                        \
      int dl0 = nh * 32 + l15;                                                \
      int sw0 = (dl0 & 7) << 3;                                               \
      bf16x8 bv0 = *(const bf16x8*)&wb[dl0 * 128 + ((kk * 32 + l4 * 8) ^ sw0)]; \
      acc0 = __builtin_amdgcn_mfma_f32_16x16x32_bf16(ha[kk], bv0, acc0, 0, 0, 0); \
      int dl1 = nh * 32 + 16 + l15;                                           \
      int sw1 = (dl1 & 7) << 3;                                               \
      bf16x8 bv1 = *(const bf16x8*)&wb[dl1 * 128 + ((kk * 32 + l4 * 8) ^ sw1)]; \
      acc1 = __builtin_amdgcn_mfma_f32_16x16x32_bf16(ha[kk], bv1, acc1, 0, 0, 0); \
    }                                                                         \
    __builtin_amdgcn_s_setprio(0);                                            \
    _Pragma("unroll") for (int r = 0; r < 4; ++r) {                           \
      float r0 = xe0[r] + (acc0[r] + bias0) * zr[r];                          \
      float r1 = xe1[r] + (acc1[r] + bias1) * zr[r];                          \
      float* p0s = valid[r] ? (out + (size_t)orow[r] * ND + d0) : (osink + tid); \
      float* p1s = valid[r] ? (out + (size_t)orow[r] * ND + d1) : (osink + tid); \
      *p0s = r0;                                                              \
      *p1s = r1;                                                              \
    }                                                                         \
    if ((c) <= 5) { BARV12; } else if ((c) == 6) { BARV10; }                  \
  } while (0)

__launch_bounds__(512, 2)
__global__ void moe_f(const float* __restrict__ x, const float* __restrict__ z,
                      const float* __restrict__ b1, const float* __restrict__ b2,
                      const unsigned short* __restrict__ w1sw,
                      const unsigned short* __restrict__ w2sw,
                      const int* __restrict__ counts, const int* __restrict__ bucket,
                      float* __restrict__ out, float* __restrict__ osink) {
  __shared__ unsigned short wt[3][8192];   // 48 KB, shared by both stages
  __shared__ unsigned short ht[64][136];   // 17 KB H exchange
  int e = blockIdx.x & 7;  // XCD pin
  int t = blockIdx.x >> 3;
  int cnt = counts[e];
  if (t * 64 >= cnt) return;  // uniform exit before any barrier
  int tid = threadIdx.x, w = tid >> 6, lane = tid & 63;
  int l15 = lane & 15, l4 = lane >> 4;
  int rg = w >> 1, nh = w & 1;

  // A-row for stage 1 (clamped, unconditional)
  int ra = t * 64 + rg * 16 + l15;
  int ras = (ra < cnt) ? ra : (cnt - 1);
  int rid = bucket[e * NB + ras];
  const float* xrow = x + (size_t)rid * ND + l4 * 8;

  const char* w1e = (const char*)w1sw + (size_t)e * NS * ND * 2;
  const char* w2e = (const char*)w2sw + (size_t)e * ND * NS * 2;
  int p0 = tid, p1 = tid + 512;
  const char* g0 = w1e + (p0 >> 3) * 1024 + (p0 & 7) * 16;
  const char* g1 = w1e + (p1 >> 3) * 1024 + (p1 & 7) * 16;

  // ---------------- stage 1 prologue (pinned issue groups) ----------------
  float4 xA[4], xB[4];
  M1LOADX(xA, 0);
  M1STAGE(0);
  CFENCE;                 // group boundary: {rid,x0,S0} older than {x1,S1}
  M1LOADX(xB, 1);
  M1STAGE(1);
  BARV6;                  // retires rid,x0,S0; leaves x1,S1 in flight

  f32x4 acc[4];
#pragma unroll
  for (int i = 0; i < 4; ++i) acc[i] = (f32x4){0.f, 0.f, 0.f, 0.f};

  M1_ITER(0, xA); M1_ITER(1, xB); M1_ITER(2, xA); M1_ITER(3, xB);
  M1_ITER(4, xA); M1_ITER(5, xB); M1_ITER(6, xA); M1_ITER(7, xB);

  // ---------------- transition: H -> LDS, stage-2 state, W2 prologue ------
#pragma unroll
  for (int nt = 0; nt < 4; ++nt) {
    int col = nh * 64 + nt * 16 + l15;
    float bias = b1[e * NS + col];
#pragma unroll
    for (int r = 0; r < 4; ++r)
      ht[rg * 16 + l4 * 4 + r][col] = f2b(fmaxf(acc[nt][r] + bias, 0.f));
  }

  int orow[4];
  bool valid[4];
  float zr[4];
#pragma unroll
  for (int r = 0; r < 4; ++r) {
    int pos = t * 64 + rg * 16 + l4 * 4 + r;
    valid[r] = (pos < cnt);
    int ps = valid[r] ? pos : (cnt - 1);
    orow[r] = bucket[e * NB + ps];
    zr[r] = z[orow[r]];
  }

  M2STAGE(0);
  CFENCE;                 // {transition loads, S2(0)} older than {S2(1)}
  M2STAGE(1);
  BARV2L;                 // retires all loads + S2(0); drains ht ds_writes

  bf16x8 ha[4];
#pragma unroll
  for (int kk = 0; kk < 4; ++kk)
    ha[kk] = *(const bf16x8*)&ht[rg * 16 + l15][kk * 32 + l4 * 8];

  // ---------------- stage 2 + fused epilogue ----------------
  M2_ITER(0); M2_ITER(1); M2_ITER(2); M2_ITER(3);
  M2_ITER(4); M2_ITER(5); M2_ITER(6); M2_ITER(7);
}

extern "C" void kernel_launch(void* const* d_in, const int* in_sizes, int n_in,
                              void* d_out, int out_size, void* d_ws, size_t ws_size,
                              hipStream_t stream) {
  const float* x = (const float*)d_in[0];
  const int* yidx = (const int*)d_in[1];
  // d_in[2] = y_hard (unused by reference)
  const float* z = (const float*)d_in[3];
  const float* W1 = (const float*)d_in[4];
  const float* b1 = (const float*)d_in[5];
  const float* W2 = (const float*)d_in[6];
  const float* b2 = (const float*)d_in[7];
  float* out = (float*)d_out;

  char* ws = (char*)d_ws;
  int* counts = (int*)ws;                     // 32 B
  int* bucket = (int*)(ws + 256);             // 1 MB
  size_t off = 256 + (size_t)NE * NB * 4;
  unsigned short* w1sw = (unsigned short*)(ws + off);  // 1 MB (swizzled)
  off += (size_t)NE * NS * ND * 2;
  unsigned short* w2sw = (unsigned short*)(ws + off);  // 1 MB (swizzled)
  off += (size_t)NE * ND * NS * 2;
  float* osink = (float*)(ws + off);          // 4 KB dummy store sink

  zero_counts_k<<<1, 64, 0, stream>>>(counts);
  bin_rows_k<<<NB / 1024, 1024, 0, stream>>>(yidx, counts, bucket);
  // W1 [E][D][S] -> [E][S][D] pre-swizzled; W2 [E][S][D] -> [E][D][S] pre-swizzled
  transpose_cvt_k<<<NE * (ND / 32) * (NS / 32), 256, 0, stream>>>(W1, w1sw, ND, NS);
  transpose_cvt_k<<<NE * (NS / 32) * (ND / 32), 256, 0, stream>>>(W2, w2sw, NS, ND);
  moe_f<<<NE * TPE, 512, 0, stream>>>(x, z, b1, b2, w1sw, w2sw, counts, bucket,
                                      out, osink);
}

// Round 18
// 67.390 us; speedup vs baseline: 1.0607x; 1.0036x over previous
//
#include <hip/hip_runtime.h>
#include <hip/hip_bf16.h>

#define NB 32768
#define ND 512
#define NS 128
#define NE 8
#define TPE 96  // 64-row tiles per expert (covers cnt up to 6144)

typedef __attribute__((ext_vector_type(8))) short bf16x8;
typedef __attribute__((ext_vector_type(4))) float f32x4;

__device__ __forceinline__ unsigned short f2b(float f) {
  union { __hip_bfloat16 h; unsigned short u; } cv;
  cv.h = __float2bfloat16(f);
  return cv.u;
}

__device__ __forceinline__ bf16x8 relu_cvt8v(float4 a, float4 b) {
  bf16x8 r;
  r[0] = (short)f2b(fmaxf(a.x, 0.f)); r[1] = (short)f2b(fmaxf(a.y, 0.f));
  r[2] = (short)f2b(fmaxf(a.z, 0.f)); r[3] = (short)f2b(fmaxf(a.w, 0.f));
  r[4] = (short)f2b(fmaxf(b.x, 0.f)); r[5] = (short)f2b(fmaxf(b.y, 0.f));
  r[6] = (short)f2b(fmaxf(b.z, 0.f)); r[7] = (short)f2b(fmaxf(b.w, 0.f));
  return r;
}

__device__ __forceinline__ void gload16(const void* gsrc, void* ldst) {
  __builtin_amdgcn_global_load_lds(
      (const __attribute__((address_space(1))) unsigned int*)gsrc,
      (__attribute__((address_space(3))) unsigned int*)ldst, 16, 0, 0);
}

// counted-vmcnt phase barriers (T4): memory clobber pins VMEM issue order.
#define BARV6  asm volatile("s_waitcnt vmcnt(6)\n\ts_barrier" ::: "memory")
#define BARV12 asm volatile("s_waitcnt vmcnt(12)\n\ts_barrier" ::: "memory")
#define BARV10 asm volatile("s_waitcnt vmcnt(10)\n\ts_barrier" ::: "memory")
#define BARV0  asm volatile("s_waitcnt vmcnt(0)\n\ts_barrier" ::: "memory")
#define BARL   asm volatile("s_waitcnt lgkmcnt(0)\n\ts_barrier" ::: "memory")
#define BARV2L asm volatile("s_waitcnt vmcnt(2) lgkmcnt(0)\n\ts_barrier" ::: "memory")
#define CFENCE asm volatile("" ::: "memory")

__global__ void zero_counts_k(int* counts) {
  if (threadIdx.x < NE) counts[threadIdx.x] = 0;
}

__global__ void bin_rows_k(const int* __restrict__ yidx, int* __restrict__ counts,
                           int* __restrict__ bucket) {
  __shared__ int lcnt[NE];
  __shared__ int lbase[NE];
  int tid = threadIdx.x;
  if (tid < NE) lcnt[tid] = 0;
  __syncthreads();
  int b = blockIdx.x * blockDim.x + tid;
  int e = yidx[b];
  int pos = atomicAdd(&lcnt[e], 1);
  __syncthreads();
  if (tid < NE) lbase[tid] = atomicAdd(&counts[tid], lcnt[tid]);
  __syncthreads();
  bucket[e * NB + lbase[e] + pos] = b;
}

// [R][C] f32 -> [C][R] bf16, XOR pre-swizzle within 64-short groups so a
// LINEAR global_load_lds copy lands bank-swizzled in LDS.
__global__ void transpose_cvt_k(const float* __restrict__ in,
                                unsigned short* __restrict__ out, int R, int C) {
  __shared__ float lt[32][33];
  int tpm = (R >> 5) * (C >> 5);
  int mat = blockIdx.x / tpm;
  int rem = blockIdx.x % tpm;
  int tcn = C >> 5;
  int tr = rem / tcn, tc = rem % tcn;
  const float* mi = in + (size_t)mat * R * C;
  unsigned short* mo = out + (size_t)mat * R * C;
  int r = threadIdx.x >> 5, c = threadIdx.x & 31;
#pragma unroll
  for (int i = 0; i < 4; ++i) {
    int rr = r + i * 8;
    lt[rr][c] = mi[(size_t)(tr * 32 + rr) * C + tc * 32 + c];
  }
  __syncthreads();
#pragma unroll
  for (int i = 0; i < 4; ++i) {
    int rr = r + i * 8;
    int orow = tc * 32 + rr;
    int d = tr * 32 + c;
    int ocol = (d & ~63) | ((d & 63) ^ ((orow & 7) << 3));
    mo[(size_t)orow * R + ocol] = f2b(lt[c][rr]);
  }
}

// ---- Fused MoE, counted-vmcnt pipeline; ht aliased into wt[2] (48 KB) ----
#define M1LOADX(DST, c)                                 \
  do {                                                  \
    const float* xp = xrow + (c) * 64;                  \
    DST[0] = *(const float4*)(xp);                      \
    DST[1] = *(const float4*)(xp + 4);                  \
    DST[2] = *(const float4*)(xp + 32);                 \
    DST[3] = *(const float4*)(xp + 36);                 \
  } while (0)

#define M1STAGE(c)                                                        \
  do {                                                                    \
    gload16(g0 + (c) * 128, (char*)wt[(c) % 3] + p0 * 16);                \
    gload16(g1 + (c) * 128, (char*)wt[(c) % 3] + p1 * 16);                \
  } while (0)

#define M1_ITER(c, CUR)                                                        \
  do {                                                                         \
    if ((c) <= 5) { M1STAGE((c) + 2); }                                        \
    bf16x8 a0 = relu_cvt8v(CUR[0], CUR[1]);                                    \
    bf16x8 a1 = relu_cvt8v(CUR[2], CUR[3]);                                    \
    if ((c) <= 5) { M1LOADX(CUR, (c) + 2); }                                   \
    const unsigned short* wb = wt[(c) % 3];                                    \
    __builtin_amdgcn_s_setprio(1);                                             \
    _Pragma("unroll") for (int nt = 0; nt < 4; ++nt) {                         \
      int n = nh * 64 + nt * 16 + l15;                                         \
      int sw = (n & 7) << 3;                                                   \
      bf16x8 b0 = *(const bf16x8*)&wb[n * 64 + ((l4 * 8) ^ sw)];               \
      bf16x8 b1v = *(const bf16x8*)&wb[n * 64 + ((32 + l4 * 8) ^ sw)];         \
      acc[nt] = __builtin_amdgcn_mfma_f32_16x16x32_bf16(a0, b0, acc[nt], 0, 0, 0);  \
      acc[nt] = __builtin_amdgcn_mfma_f32_16x16x32_bf16(a1, b1v, acc[nt], 0, 0, 0); \
    }                                                                          \
    __builtin_amdgcn_s_setprio(0);                                             \
    if ((c) <= 5) { BARV6; } else if ((c) == 6) { BARV0; }                     \
  } while (0)

#define M2STAGE(c)                                                           \
  do {                                                                       \
    gload16(w2e + (c) * 16384 + p0 * 16, (char*)wt[(c) % 3] + p0 * 16);      \
    gload16(w2e + (c) * 16384 + p1 * 16, (char*)wt[(c) % 3] + p1 * 16);      \
  } while (0)

#define M2_ITER(c)                                                            \
  do {                                                                        \
    if ((c) <= 5) { M2STAGE((c) + 2); }                                       \
    float xe0[4], xe1[4];                                                     \
    int d0 = (c) * 64 + nh * 32 + l15;                                        \
    int d1 = d0 + 16;                                                         \
    _Pragma("unroll") for (int r = 0; r < 4; ++r) {                           \
      xe0[r] = x[(size_t)orow[r] * ND + d0];                                  \
      xe1[r] = x[(size_t)orow[r] * ND + d1];                                  \
    }                                                                         \
    float bias0 = b2[e * ND + d0];                                            \
    float bias1 = b2[e * ND + d1];                                            \
    const unsigned short* wb = wt[(c) % 3];                                   \
    f32x4 acc0 = (f32x4){0.f, 0.f, 0.f, 0.f};                                 \
    f32x4 acc1 = (f32x4){0.f, 0.f, 0.f, 0.f};                                 \
    __builtin_amdgcn_s_setprio(1);                                            \
    _Pragma("unroll") for (int kk = 0; kk < 4; ++kk) {                        \
      int dl0 = nh * 32 + l15;                                                \
      int sw0 = (dl0 & 7) << 3;                                               \
      bf16x8 bv0 = *(const bf16x8*)&wb[dl0 * 128 + ((kk * 32 + l4 * 8) ^ sw0)]; \
      acc0 = __builtin_amdgcn_mfma_f32_16x16x32_bf16(ha[kk], bv0, acc0, 0, 0, 0); \
      int dl1 = nh * 32 + 16 + l15;                                           \
      int sw1 = (dl1 & 7) << 3;                                               \
      bf16x8 bv1 = *(const bf16x8*)&wb[dl1 * 128 + ((kk * 32 + l4 * 8) ^ sw1)]; \
      acc1 = __builtin_amdgcn_mfma_f32_16x16x32_bf16(ha[kk], bv1, acc1, 0, 0, 0); \
    }                                                                         \
    __builtin_amdgcn_s_setprio(0);                                            \
    _Pragma("unroll") for (int r = 0; r < 4; ++r) {                           \
      float r0 = xe0[r] + (acc0[r] + bias0) * zr[r];                          \
      float r1 = xe1[r] + (acc1[r] + bias1) * zr[r];                          \
      float* p0s = valid[r] ? (out + (size_t)orow[r] * ND + d0) : (osink + tid); \
      float* p1s = valid[r] ? (out + (size_t)orow[r] * ND + d1) : (osink + tid); \
      *p0s = r0;                                                              \
      *p1s = r1;                                                              \
    }                                                                         \
    if ((c) <= 5) { BARV12; } else if ((c) == 6) { BARV10; }                  \
  } while (0)

__launch_bounds__(512, 6)
__global__ void moe_f(const float* __restrict__ x, const float* __restrict__ z,
                      const float* __restrict__ b1, const float* __restrict__ b2,
                      const unsigned short* __restrict__ w1sw,
                      const unsigned short* __restrict__ w2sw,
                      const int* __restrict__ counts, const int* __restrict__ bucket,
                      float* __restrict__ out, float* __restrict__ osink) {
  __shared__ unsigned short wt[3][8192];   // 48 KB; wt[2] doubles as H exchange
  char* htb = (char*)wt[2];                // ht[64][128] bf16, XOR-swizzled
  int e = blockIdx.x & 7;  // XCD pin
  int t = blockIdx.x >> 3;
  int cnt = counts[e];
  if (t * 64 >= cnt) return;  // uniform exit before any barrier
  int tid = threadIdx.x, w = tid >> 6, lane = tid & 63;
  int l15 = lane & 15, l4 = lane >> 4;
  int rg = w >> 1, nh = w & 1;

  // A-row for stage 1 (clamped, unconditional)
  int ra = t * 64 + rg * 16 + l15;
  int ras = (ra < cnt) ? ra : (cnt - 1);
  int rid = bucket[e * NB + ras];
  const float* xrow = x + (size_t)rid * ND + l4 * 8;

  const char* w1e = (const char*)w1sw + (size_t)e * NS * ND * 2;
  const char* w2e = (const char*)w2sw + (size_t)e * ND * NS * 2;
  int p0 = tid, p1 = tid + 512;
  const char* g0 = w1e + (p0 >> 3) * 1024 + (p0 & 7) * 16;
  const char* g1 = w1e + (p1 >> 3) * 1024 + (p1 & 7) * 16;

  // ---------------- stage 1 prologue (pinned issue groups) ----------------
  float4 xA[4], xB[4];
  M1LOADX(xA, 0);
  M1STAGE(0);
  CFENCE;                 // group boundary: {rid,x0,S0} older than {x1,S1}
  M1LOADX(xB, 1);
  M1STAGE(1);
  BARV6;                  // retires rid,x0,S0; leaves x1,S1 in flight

  f32x4 acc[4];
#pragma unroll
  for (int i = 0; i < 4; ++i) acc[i] = (f32x4){0.f, 0.f, 0.f, 0.f};

  M1_ITER(0, xA); M1_ITER(1, xB); M1_ITER(2, xA); M1_ITER(3, xB);
  M1_ITER(4, xA); M1_ITER(5, xB); M1_ITER(6, xA); M1_ITER(7, xB);
  // phase 7 has no end barrier; wt[2] is free (all waves past phase-6 BARV0)

  // ------- transition: H -> wt[2] (swizzled), row state, W2 prologue -------
#pragma unroll
  for (int nt = 0; nt < 4; ++nt) {
    int col = nh * 64 + nt * 16 + l15;
    float bias = b1[e * NS + col];
#pragma unroll
    for (int r = 0; r < 4; ++r) {
      int row = rg * 16 + l4 * 4 + r;
      int off = (row * 256 + col * 2) ^ ((row & 7) << 4);
      *(unsigned short*)(htb + off) = f2b(fmaxf(acc[nt][r] + bias, 0.f));
    }
  }

  int orow[4];
  bool valid[4];
  float zr[4];
#pragma unroll
  for (int r = 0; r < 4; ++r) {
    int pos = t * 64 + rg * 16 + l4 * 4 + r;
    valid[r] = (pos < cnt);
    int ps = valid[r] ? pos : (cnt - 1);
    orow[r] = bucket[e * NB + ps];
    zr[r] = z[orow[r]];
  }

  M2STAGE(0);             // wt[0]: safe, all waves past phase-6 barrier
  BARL;                   // ht visible to all; phase-7 wt[1] readers done
  M2STAGE(1);             // wt[1]: now safe (race in R15 fixed here)

  bf16x8 ha[4];
#pragma unroll
  for (int kk = 0; kk < 4; ++kk) {
    int row = rg * 16 + l15;
    int off = (row * 256 + (kk * 32 + l4 * 8) * 2) ^ ((row & 7) << 4);
    ha[kk] = *(const bf16x8*)(htb + off);
  }
  BARV2L;                 // retires S2(0)+older; ha reads drained before S2(2)

  // ---------------- stage 2 + fused epilogue ----------------
  M2_ITER(0); M2_ITER(1); M2_ITER(2); M2_ITER(3);
  M2_ITER(4); M2_ITER(5); M2_ITER(6); M2_ITER(7);
}

extern "C" void kernel_launch(void* const* d_in, const int* in_sizes, int n_in,
                              void* d_out, int out_size, void* d_ws, size_t ws_size,
                              hipStream_t stream) {
  const float* x = (const float*)d_in[0];
  const int* yidx = (const int*)d_in[1];
  // d_in[2] = y_hard (unused by reference)
  const float* z = (const float*)d_in[3];
  const float* W1 = (const float*)d_in[4];
  const float* b1 = (const float*)d_in[5];
  const float* W2 = (const float*)d_in[6];
  const float* b2 = (const float*)d_in[7];
  float* out = (float*)d_out;

  char* ws = (char*)d_ws;
  int* counts = (int*)ws;                     // 32 B
  int* bucket = (int*)(ws + 256);             // 1 MB
  size_t off = 256 + (size_t)NE * NB * 4;
  unsigned short* w1sw = (unsigned short*)(ws + off);  // 1 MB (swizzled)
  off += (size_t)NE * NS * ND * 2;
  unsigned short* w2sw = (unsigned short*)(ws + off);  // 1 MB (swizzled)
  off += (size_t)NE * ND * NS * 2;
  float* osink = (float*)(ws + off);          // 4 KB dummy store sink

  zero_counts_k<<<1, 64, 0, stream>>>(counts);
  bin_rows_k<<<NB / 1024, 1024, 0, stream>>>(yidx, counts, bucket);
  // W1 [E][D][S] -> [E][S][D] pre-swizzled; W2 [E][S][D] -> [E][D][S] pre-swizzled
  transpose_cvt_k<<<NE * (ND / 32) * (NS / 32), 256, 0, stream>>>(W1, w1sw, ND, NS);
  transpose_cvt_k<<<NE * (NS / 32) * (ND / 32), 256, 0, stream>>>(W2, w2sw, NS, ND);
  moe_f<<<NE * TPE, 512, 0, stream>>>(x, z, b1, b2, w1sw, w2sw, counts, bucket,
                                      out, osink);
}